// Round 13
// baseline (234.987 us; speedup 1.0000x reference)
//
#include <hip/hip_runtime.h>

// ---------------------------------------------------------------------------
// GAT (2-layer, dense mask) on gfx950 — R13.
// vs R11 (175.4 us, best): k_final folded into k_att2 via the last-finisher
// pattern — att2 keeps its proven (64,16)=1024-block shape; each block
// threadfence+atomicAdd's a per-iblk counter (zeroed by k_gemm2, no memset
// node); the 16th arriver combines that iblk's 64 rows + elu + log_softmax.
// R12's naive fusion (256 blocks) cost 3x the kernels it replaced — blocks
// matter more than launches for these small kernels.
// gemm1/att1/gemm2 byte-identical to R11. 4 launches.
// ---------------------------------------------------------------------------

typedef _Float16 h2 __attribute__((ext_vector_type(2)));
typedef _Float16 half8 __attribute__((ext_vector_type(8)));
typedef __attribute__((ext_vector_type(4))) float f32x4;
typedef unsigned long long u64;
typedef unsigned short u16;
typedef unsigned int u32;

__device__ __forceinline__ u16 f2h(float f){
  union { _Float16 h; u16 u; } c; c.h = (_Float16)f; return c.u;
}
__device__ __forceinline__ h2 u2h2(u32 u){ union { u32 u; h2 h; } c; c.u = u; return c.h; }
__device__ __forceinline__ u32 h22u(h2 h){ union { u32 u; h2 h; } c; c.h = h; return c.u; }
__device__ __forceinline__ half8 pk2h8(uint4 v){ union { uint4 u; half8 h; } c; c.u = v; return c.h; }

__device__ __forceinline__ void async16(void* lds, const void* g){
  __builtin_amdgcn_global_load_lds((const __attribute__((address_space(1))) u32*)g,
                                   (__attribute__((address_space(3))) u32*)lds, 16, 0, 0);
}
__device__ __forceinline__ void async4(void* lds, const void* g){
  __builtin_amdgcn_global_load_lds((const __attribute__((address_space(1))) u32*)g,
                                   (__attribute__((address_space(3))) u32*)lds, 4, 0, 0);
}

// ===== K1: Wh = x @ W[h] (self-packing) + tables + whB + adj slice =========
__global__ __launch_bounds__(256) void k_gemm1(const float* __restrict__ x,
                                               const float* __restrict__ W,
                                               const float* __restrict__ av,
                                               const int* __restrict__ adj,
                                               u16* __restrict__ whB,
                                               u64* __restrict__ bits_t,
                                               float* __restrict__ r1,
                                               u16* __restrict__ e21h, u16* __restrict__ e202h){
  __shared__ u16 wLDS[32768];              // [fgb 0..63][o 0..63][q 0..7] f16, 64 KB
  __shared__ u16 tr[4096];                 // 8 KB transpose buffer
  int h    = blockIdx.y;
  int nblk = blockIdx.x;
  int tid  = threadIdx.x;
  int lane = tid & 63;
  int wv   = tid >> 6;
  int row16 = lane & 15, grp = lane >> 4;
  int n0 = nblk * 64;
  int n0w = n0 + wv * 16;

  // ---- stage W[h] f32 -> f16 B-layout in LDS ----
  {
    int o = tid & 63, fb0 = tid >> 6;      // 4 fgb per iteration
    for (int k = 0; k < 16; ++k){
      int fgb = fb0 + k * 4;
      const float* src = W + ((size_t)h * 512 + fgb * 8) * 64 + o;
      u32 pk[4];
      #pragma unroll
      for (int p = 0; p < 4; ++p)
        pk[p] = (u32)f2h(src[(2 * p) * 64]) | ((u32)f2h(src[(2 * p + 1) * 64]) << 16);
      *(uint4*)(wLDS + ((size_t)fgb * 64 + o) * 8) = *(uint4*)pk;
    }
  }
  __syncthreads();

  f32x4 acc[4] = {};
  #pragma unroll 4
  for (int ks = 0; ks < 16; ++ks){
    int fgb = ks * 4 + grp;
    const float* xs = x + (size_t)(n0w + row16) * 512 + fgb * 8;
    float4 xv0 = ((const float4*)xs)[0];
    float4 xv1 = ((const float4*)xs)[1];
    u32 ax[4];
    ax[0] = (u32)f2h(xv0.x) | ((u32)f2h(xv0.y) << 16);
    ax[1] = (u32)f2h(xv0.z) | ((u32)f2h(xv0.w) << 16);
    ax[2] = (u32)f2h(xv1.x) | ((u32)f2h(xv1.y) << 16);
    ax[3] = (u32)f2h(xv1.z) | ((u32)f2h(xv1.w) << 16);
    half8 af = pk2h8(*(uint4*)ax);
    #pragma unroll
    for (int nt = 0; nt < 4; ++nt){
      half8 bf = *(const half8*)(wLDS + ((size_t)fgb * 64 + nt * 16 + row16) * 8);
      acc[nt] = __builtin_amdgcn_mfma_f32_16x16x32_f16(af, bf, acc[nt], 0, 0, 0);
    }
  }
  // ---- scale-free score tables ----
  float a1v[4], a2v[4];
  #pragma unroll
  for (int nt = 0; nt < 4; ++nt){
    a1v[nt] = av[h * 128 + nt * 16 + row16];
    a2v[nt] = av[h * 128 + 64 + nt * 16 + row16];
  }
  #pragma unroll
  for (int r = 0; r < 4; ++r){
    float p1 = acc[0][r]*a1v[0] + acc[1][r]*a1v[1] + acc[2][r]*a1v[2] + acc[3][r]*a1v[3];
    float p2 = acc[0][r]*a2v[0] + acc[1][r]*a2v[1] + acc[2][r]*a2v[2] + acc[3][r]*a2v[3];
    #pragma unroll
    for (int d = 1; d < 16; d <<= 1){ p1 += __shfl_xor(p1, d, 64); p2 += __shfl_xor(p2, d, 64); }
    if (row16 == 0){
      int idx = h * 4096 + n0w + grp * 4 + r;
      r1[idx]    = __expf(-0.8f * p1);     // row scale e^{-0.8 s1}
      e21h[idx]  = f2h(__expf(p2));
      e202h[idx] = f2h(__expf(0.2f * p2));
    }
  }
  // ---- whB f16 pack via LDS transpose ----
  #pragma unroll
  for (int nt = 0; nt < 4; ++nt)
    #pragma unroll
    for (int r = 0; r < 4; ++r){
      int jl = wv * 16 + grp * 4 + r;
      int o  = nt * 16 + row16;
      tr[((jl >> 3) * 64 + o) * 8 + (jl & 7)] = f2h(acc[nt][r]);
    }
  __syncthreads();
  u16* dst = whB + (size_t)h * 262144 + (size_t)n0 * 64;
  #pragma unroll
  for (int q = 0; q < 2; ++q)
    *(uint4*)(dst + (tid * 2 + q) * 8) = *(const uint4*)(tr + (tid * 2 + q) * 8);

  // ---- adj-pack slice (transposed bitmask; no data dep on gemm) ----
  {
    int B = blockIdx.y * 64 + blockIdx.x;   // 0..511
    int uid0 = B * 512 + wv * 128;
    for (int k = 0; k < 128; k += 8){
      int v[8];
      #pragma unroll
      for (int q = 0; q < 8; ++q){
        int uid = uid0 + k + q;
        v[q] = adj[(size_t)(uid >> 6) * 4096 + ((uid & 63) << 6) + lane];
      }
      u64 m[8];
      #pragma unroll
      for (int q = 0; q < 8; ++q) m[q] = __ballot(v[q] != 0);
      if (lane == 0){
        #pragma unroll
        for (int q = 0; q < 8; ++q){
          int uid = uid0 + k + q;
          bits_t[(size_t)(uid & 63) * 4096 + (uid >> 6)] = m[q];
        }
      }
    }
  }
}

// ===== K2: layer-1 attention (R7 structure, f16 + packed w-gen) ============
__global__ __launch_bounds__(256) void k_att1(const u16* __restrict__ whB,
                                              const u64* __restrict__ bits_t,
                                              const float* __restrict__ r1,
                                              const u16* __restrict__ e21h, const u16* __restrict__ e202h,
                                              u16* __restrict__ pnum, float* __restrict__ pden){
  __shared__ u16  smB[2][4096];            // 64 j x 64 o f16, [j/8][o][j&7]
  __shared__ u32  smT[2][2][64];           // staged f16 tables
  __shared__ u32  smLut[4];
  int h     = blockIdx.y;
  int iblk  = blockIdx.x;
  int split = blockIdx.z;
  int lane = threadIdx.x & 63;
  int wv   = threadIdx.x >> 6;
  int row16 = lane & 15, grp = lane >> 4;
  if (threadIdx.x < 4)
    smLut[threadIdx.x] = ((threadIdx.x & 1) ? 0xFFFFu : 0u) | ((threadIdx.x & 2) ? 0xFFFF0000u : 0u);
  int i = iblk * 64 + wv * 16 + row16;
  int hoff = h * 4096;
  u32 rb = (u32)f2h(r1[hoff + i]); rb |= rb << 16;
  h2 rr = u2h2(rb);
  const u16* whBh = whB + (size_t)h * 262144;
  int jbeg = split * 1024;

  half8 bden;                              // ones-column B frag for den
  {
    u32 z[4] = {0,0,0,0};
    if (row16 == 0){ z[0]=0x3C003C00u; z[1]=0x3C003C00u; z[2]=0x3C003C00u; z[3]=0x3C003C00u; }
    bden = pk2h8(*(uint4*)z);
  }

  auto stage = [&](int bb, int j0){
    const char* g = (const char*)whBh + (size_t)j0 * 128 + wv * 2048 + lane * 16;
    char* l = (char*)(&smB[bb][0]) + wv * 2048;
    async16(l, g);
    async16(l + 1024, g + 1024);
    if (wv == 0)      async4(&smT[bb][0][0], (const char*)(e21h  + hoff + j0) + lane * 4);
    else if (wv == 1) async4(&smT[bb][1][0], (const char*)(e202h + hoff + j0) + lane * 4);
  };

  f32x4 acc[4] = {};
  f32x4 accden = {};
  stage(0, jbeg);
  for (int c = 0; c < 16; ++c){
    int bb = c & 1;
    u64 mrow = bits_t[(size_t)(split * 16 + c) * 4096 + i];   // coalesced
    __syncthreads();                       // buf bb staged; buf bb^1 free
    if (c < 15) stage(bb ^ 1, jbeg + (c + 1) * 64);
    #pragma unroll
    for (int ks = 0; ks < 2; ++ks){
      uint4 e1q = *(const uint4*)((const char*)&smT[bb][0][0] + ks * 64 + grp * 16);
      uint4 e2q = *(const uint4*)((const char*)&smT[bb][1][0] + ks * 64 + grp * 16);
      u32 es[4] = {e1q.x, e1q.y, e1q.z, e1q.w};
      u32 gs[4] = {e2q.x, e2q.y, e2q.z, e2q.w};
      const u16* bbase = &smB[bb][(ks * 4 + grp) * 512];
      half8 bf0 = *(const half8*)(bbase + (0 * 16 + row16) * 8);
      half8 bf1 = *(const half8*)(bbase + (1 * 16 + row16) * 8);
      half8 bf2 = *(const half8*)(bbase + (2 * 16 + row16) * 8);
      half8 bf3 = *(const half8*)(bbase + (3 * 16 + row16) * 8);
      u32 mb = ((u32)(mrow >> (ks * 32)) >> (grp * 8)) & 0xffu;
      u32 pk[4];
      #pragma unroll
      for (int t2i = 0; t2i < 4; ++t2i){
        h2 w = __builtin_elementwise_max(u2h2(es[t2i]), rr * u2h2(gs[t2i]));
        pk[t2i] = h22u(w) & smLut[(mb >> (2 * t2i)) & 3u];
      }
      half8 af = pk2h8(*(uint4*)pk);
      acc[0] = __builtin_amdgcn_mfma_f32_16x16x32_f16(af, bf0, acc[0], 0, 0, 0);
      acc[1] = __builtin_amdgcn_mfma_f32_16x16x32_f16(af, bf1, acc[1], 0, 0, 0);
      acc[2] = __builtin_amdgcn_mfma_f32_16x16x32_f16(af, bf2, acc[2], 0, 0, 0);
      acc[3] = __builtin_amdgcn_mfma_f32_16x16x32_f16(af, bf3, acc[3], 0, 0, 0);
      accden = __builtin_amdgcn_mfma_f32_16x16x32_f16(af, bden, accden, 0, 0, 0);
    }
  }

  #pragma unroll
  for (int r4 = 0; r4 < 4; ++r4){
    int n = iblk * 64 + wv * 16 + grp * 4 + r4;
    if (row16 == 0)
      pden[((size_t)split * 8 + h) * 4096 + n] = accden[r4];
    u16* dst = pnum + ((size_t)split * 4096 + n) * 512 + h * 64 + row16;
    #pragma unroll
    for (int nt = 0; nt < 4; ++nt)
      dst[nt * 16] = f2h(acc[nt][r4]);
  }
}

// ===== K3: combine + Who = h @ Wout + layer-2 tables (+ counter init) ======
__global__ __launch_bounds__(256) void k_gemm2(const u16* __restrict__ pnum,
                                               const float* __restrict__ pden,
                                               const float* __restrict__ Wout,
                                               const float* __restrict__ aout,
                                               u16* __restrict__ whoB,
                                               float* __restrict__ r1o,
                                               u16* __restrict__ e21oh, u16* __restrict__ e202oh,
                                               u32* __restrict__ cnt){
  __shared__ float Wl[8192];                  // 512 x 16
  __shared__ float hrow[16 * 516];            // combined+elu rows, padded stride
  __shared__ float sden[128];                 // den[h][n]
  int n0 = blockIdx.x * 16;
  if (blockIdx.x < 64 && threadIdx.x == 0) cnt[blockIdx.x] = 0;  // att2 finisher counters
  for (int t = threadIdx.x; t < 8192; t += 256) Wl[t] = Wout[t];
  if (threadIdx.x < 128){
    int hh = threadIdx.x >> 4, nn = threadIdx.x & 15;
    float d = 0.f;
    #pragma unroll
    for (int s = 0; s < 4; ++s) d += pden[((size_t)s * 8 + hh) * 4096 + n0 + nn];
    sden[threadIdx.x] = d;
  }
  __syncthreads();
  {
    int nn = threadIdx.x >> 4;
    int fc = threadIdx.x & 15;
    int f0 = fc * 32;
    int hh = fc >> 1;
    float dinv = 1.f / sden[hh * 16 + nn];
    float v[32];
    #pragma unroll
    for (int k = 0; k < 32; ++k) v[k] = 0.f;
    #pragma unroll
    for (int s = 0; s < 4; ++s){
      const u16* p = pnum + ((size_t)s * 4096 + n0 + nn) * 512 + f0;
      #pragma unroll
      for (int q = 0; q < 4; ++q){
        uint4 raw = *(const uint4*)(p + q * 8);
        u32 rw[4] = {raw.x, raw.y, raw.z, raw.w};
        #pragma unroll
        for (int d2 = 0; d2 < 4; ++d2){
          h2 dh = u2h2(rw[d2]);
          v[q * 8 + d2 * 2]     += (float)dh.x;
          v[q * 8 + d2 * 2 + 1] += (float)dh.y;
        }
      }
    }
    #pragma unroll
    for (int k = 0; k < 32; ++k){
      float val = v[k] * dinv;
      val = val > 0.f ? val : (__expf(val) - 1.f);
      hrow[nn * 516 + f0 + k] = val;
    }
  }
  __syncthreads();
  int c  = threadIdx.x & 15;
  int rl = threadIdx.x >> 4;
  int n = n0 + rl;
  const float4* hr = (const float4*)(hrow + rl * 516);
  float acc = 0.f;
  #pragma unroll 8
  for (int f4 = 0; f4 < 128; ++f4){
    float4 hv = hr[f4];
    int f = f4 * 4;
    acc += hv.x * Wl[f * 16 + c] + hv.y * Wl[(f + 1) * 16 + c]
         + hv.z * Wl[(f + 2) * 16 + c] + hv.w * Wl[(f + 3) * 16 + c];
  }
  whoB[((size_t)(n >> 3) * 16 + c) * 8 + (n & 7)] = f2h(acc);
  float p1 = acc * aout[c], p2 = acc * aout[16 + c];
  #pragma unroll
  for (int d = 1; d < 16; d <<= 1){ p1 += __shfl_xor(p1, d, 64); p2 += __shfl_xor(p2, d, 64); }
  if (c == 0){
    r1o[n]    = __expf(-0.8f * p1);
    e21oh[n]  = f2h(__expf(p2));
    e202oh[n] = f2h(__expf(0.2f * p2));
  }
}

// ===== K4: layer-2 attention (R11 shape) + last-finisher final =============
// grid (64,16) = 1024 blocks; finisher (16th arriver per iblk) combines the
// iblk's 64 rows: sum splits, /den, elu, log_softmax -> out.
__global__ __launch_bounds__(256) void k_att2(const u16* __restrict__ whoB,
                                              const u64* __restrict__ bits_t,
                                              const float* __restrict__ r1o,
                                              const u16* __restrict__ e21oh, const u16* __restrict__ e202oh,
                                              float* __restrict__ pnum, float* __restrict__ pden,
                                              u32* __restrict__ cnt,
                                              float* __restrict__ out){
  __shared__ u32 smLut[4];
  __shared__ u32 s_last;
  int iblk  = blockIdx.x;
  int split = blockIdx.y;                     // 0..15
  int tid  = threadIdx.x;
  int lane = tid & 63;
  int wv   = tid >> 6;
  int row16 = lane & 15, grp = lane >> 4;
  if (tid < 4)
    smLut[tid] = ((tid & 1) ? 0xFFFFu : 0u) | ((tid & 2) ? 0xFFFF0000u : 0u);
  __syncthreads();
  int i = iblk * 64 + wv * 16 + row16;
  u32 rb = (u32)f2h(r1o[i]); rb |= rb << 16;
  h2 rr = u2h2(rb);
  int jbeg = split * 256;
  half8 bden;
  {
    u32 z[4] = {0,0,0,0};
    if (row16 == 0){ z[0]=0x3C003C00u; z[1]=0x3C003C00u; z[2]=0x3C003C00u; z[3]=0x3C003C00u; }
    bden = pk2h8(*(uint4*)z);
  }

  f32x4 acc = {};
  f32x4 accden = {};
  #pragma unroll
  for (int c = 0; c < 4; ++c){
    int j0 = jbeg + c * 64;
    u64 mrow = bits_t[(size_t)(split * 4 + c) * 4096 + i];   // coalesced
    #pragma unroll
    for (int ks = 0; ks < 2; ++ks){
      int sb = (j0 >> 3) + ks * 4 + grp;
      half8 bf = *(const half8*)(whoB + ((size_t)sb * 16 + row16) * 8);
      uint4 e1q = *(const uint4*)(e21oh  + j0 + ks * 32 + grp * 8);
      uint4 e2q = *(const uint4*)(e202oh + j0 + ks * 32 + grp * 8);
      u32 es[4] = {e1q.x, e1q.y, e1q.z, e1q.w};
      u32 gs[4] = {e2q.x, e2q.y, e2q.z, e2q.w};
      u32 mb = ((u32)(mrow >> (ks * 32)) >> (grp * 8)) & 0xffu;
      u32 pk[4];
      #pragma unroll
      for (int t2i = 0; t2i < 4; ++t2i){
        h2 w = __builtin_elementwise_max(u2h2(es[t2i]), rr * u2h2(gs[t2i]));
        pk[t2i] = h22u(w) & smLut[(mb >> (2 * t2i)) & 3u];
      }
      half8 af = pk2h8(*(uint4*)pk);
      acc    = __builtin_amdgcn_mfma_f32_16x16x32_f16(af, bf, acc, 0, 0, 0);
      accden = __builtin_amdgcn_mfma_f32_16x16x32_f16(af, bden, accden, 0, 0, 0);
    }
  }
  #pragma unroll
  for (int r4 = 0; r4 < 4; ++r4){
    int n = iblk * 64 + wv * 16 + grp * 4 + r4;
    if (row16 == 0)
      pden[(size_t)n * 16 + split] = accden[r4];
    pnum[((size_t)n * 16 + split) * 16 + row16] = acc[r4];
  }

  // ---- last-finisher: 16th arriver per iblk combines + final ----
  __syncthreads();                            // all partial stores issued
  if (tid == 0){
    __threadfence();                          // release partials device-wide
    u32 o = __hip_atomic_fetch_add(&cnt[iblk], 1u, __ATOMIC_ACQ_REL, __HIP_MEMORY_SCOPE_AGENT);
    s_last = (o == 15u);
  }
  __syncthreads();
  if (s_last){
    __threadfence();                          // acquire all splits' partials
    #pragma unroll
    for (int q = 0; q < 4; ++q){
      int row = iblk * 64 + q * 16 + (tid >> 4);
      int c = tid & 15;
      float num = 0.f, den = 0.f;
      #pragma unroll
      for (int s = 0; s < 16; ++s){
        num += pnum[((size_t)row * 16 + s) * 16 + c];
        den += pden[(size_t)row * 16 + s];
      }
      float v = num / den;
      v = v > 0.f ? v : (__expf(v) - 1.f);
      float m = v;
      #pragma unroll
      for (int d = 1; d < 16; d <<= 1) m = fmaxf(m, __shfl_xor(m, d, 64));
      float es = __expf(v - m), ss = es;
      #pragma unroll
      for (int d = 1; d < 16; d <<= 1) ss += __shfl_xor(ss, d, 64);
      out[(size_t)row * 16 + c] = v - m - __logf(ss);
    }
  }
}

// ---------------------------------------------------------------------------
extern "C" void kernel_launch(void* const* d_in, const int* in_sizes, int n_in,
                              void* d_out, int out_size, void* d_ws, size_t ws_size,
                              hipStream_t stream){
  (void)in_sizes; (void)n_in; (void)out_size; (void)ws_size;
  const float* x    = (const float*)d_in[0];
  const int*   adj  = (const int*)d_in[1];
  const float* W    = (const float*)d_in[2];
  const float* av   = (const float*)d_in[3];
  const float* Wout = (const float*)d_in[4];
  const float* aout = (const float*)d_in[5];
  float* out = (float*)d_out;
  char* ws = (char*)d_ws;

  u64*  bits_t  = (u64*)(ws + 0x0000000);        // 2 MB [64][4096]
  u16*  whB     = (u16*)(ws + 0x0200000);        // 4 MB f16 [8][j/8][o][8]
  float* r1     = (float*)(ws + 0x0600000);      // 128 KB
  u16*  e21h    = (u16*)(ws + 0x0620000);        // 64 KB f16
  u16*  e202h   = (u16*)(ws + 0x0630000);        // 64 KB f16
  u16*  pnum1   = (u16*)(ws + 0x0680000);        // 16 MB f16 [4][4096][512]
  float* pden1  = (float*)(ws + 0x1680000);      // 512 KB [4][8][4096]
  u16*  whoB    = (u16*)(ws + 0x1700000);        // 128 KB f16
  float* r1o    = (float*)(ws + 0x1720000);      // 16 KB
  u16*  e21oh   = (u16*)(ws + 0x1724000);        // 8 KB f16
  u16*  e202oh  = (u16*)(ws + 0x1726000);        // 8 KB f16
  float* pnum2  = (float*)(ws + 0x1730000);      // 4 MB [4096][16][16]
  float* pden2  = (float*)(ws + 0x1B30000);      // 256 KB [4096][16]
  u32*  cnt     = (u32*)(ws + 0x1B70000);        // 256 B (64 counters)

  k_gemm1<<<dim3(64, 8), dim3(256), 0, stream>>>(x, W, av, adj, whB, bits_t, r1, e21h, e202h);
  k_att1<<<dim3(64, 8, 4), dim3(256), 0, stream>>>(whB, bits_t, r1, e21h, e202h, pnum1, pden1);
  k_gemm2<<<dim3(256), dim3(256), 0, stream>>>(pnum1, pden1, Wout, aout, whoB, r1o, e21oh, e202oh, cnt);
  k_att2<<<dim3(64, 16), dim3(256), 0, stream>>>(whoB, bits_t, r1o, e21oh, e202oh, pnum2, pden2, cnt, out);
}

// Round 14
// 174.721 us; speedup vs baseline: 1.3449x; 1.3449x over previous
//
#include <hip/hip_runtime.h>

// ---------------------------------------------------------------------------
// GAT (2-layer, dense mask) on gfx950 — R14 = exact revert to R11 (175.4 us,
// session best). R12 (fewer-block fusion, +24 us GPU) and R13 (last-finisher
// fence, +60 us) both regressed — third confirmation that in-kernel
// device-scope sync costs 50-250 us on 8-XCD non-coherent L2s. R11's 5-launch
// decomposition is the empirical optimum: f16 MFMA everywhere, packed-f16
// w-gen (v_pk_mul/v_pk_max), scale-free weights w' = max(e^{s2},
// e^{-0.8 s1} e^{0.2 s2}), transposed coalesced bitmask, LDS-dbuf att1 at
// 2048 blocks (8/CU), gemm1 self-stages W + folds adj-pack.
// ---------------------------------------------------------------------------

typedef _Float16 h2 __attribute__((ext_vector_type(2)));
typedef _Float16 half8 __attribute__((ext_vector_type(8)));
typedef __attribute__((ext_vector_type(4))) float f32x4;
typedef unsigned long long u64;
typedef unsigned short u16;
typedef unsigned int u32;

__device__ __forceinline__ u16 f2h(float f){
  union { _Float16 h; u16 u; } c; c.h = (_Float16)f; return c.u;
}
__device__ __forceinline__ h2 u2h2(u32 u){ union { u32 u; h2 h; } c; c.u = u; return c.h; }
__device__ __forceinline__ u32 h22u(h2 h){ union { u32 u; h2 h; } c; c.h = h; return c.u; }
__device__ __forceinline__ half8 pk2h8(uint4 v){ union { uint4 u; half8 h; } c; c.u = v; return c.h; }

__device__ __forceinline__ void async16(void* lds, const void* g){
  __builtin_amdgcn_global_load_lds((const __attribute__((address_space(1))) u32*)g,
                                   (__attribute__((address_space(3))) u32*)lds, 16, 0, 0);
}
__device__ __forceinline__ void async4(void* lds, const void* g){
  __builtin_amdgcn_global_load_lds((const __attribute__((address_space(1))) u32*)g,
                                   (__attribute__((address_space(3))) u32*)lds, 4, 0, 0);
}

// ===== K1: Wh = x @ W[h] (self-packing) + tables + whB + adj slice =========
__global__ __launch_bounds__(256) void k_gemm1(const float* __restrict__ x,
                                               const float* __restrict__ W,
                                               const float* __restrict__ av,
                                               const int* __restrict__ adj,
                                               u16* __restrict__ whB,
                                               u64* __restrict__ bits_t,
                                               float* __restrict__ r1,
                                               u16* __restrict__ e21h, u16* __restrict__ e202h){
  __shared__ u16 wLDS[32768];              // [fgb 0..63][o 0..63][q 0..7] f16, 64 KB
  __shared__ u16 tr[4096];                 // 8 KB transpose buffer
  int h    = blockIdx.y;
  int nblk = blockIdx.x;
  int tid  = threadIdx.x;
  int lane = tid & 63;
  int wv   = tid >> 6;
  int row16 = lane & 15, grp = lane >> 4;
  int n0 = nblk * 64;
  int n0w = n0 + wv * 16;

  // ---- stage W[h] f32 -> f16 B-layout in LDS ----
  {
    int o = tid & 63, fb0 = tid >> 6;      // 4 fgb per iteration
    for (int k = 0; k < 16; ++k){
      int fgb = fb0 + k * 4;
      const float* src = W + ((size_t)h * 512 + fgb * 8) * 64 + o;
      u32 pk[4];
      #pragma unroll
      for (int p = 0; p < 4; ++p)
        pk[p] = (u32)f2h(src[(2 * p) * 64]) | ((u32)f2h(src[(2 * p + 1) * 64]) << 16);
      *(uint4*)(wLDS + ((size_t)fgb * 64 + o) * 8) = *(uint4*)pk;
    }
  }
  __syncthreads();

  f32x4 acc[4] = {};
  #pragma unroll 4
  for (int ks = 0; ks < 16; ++ks){
    int fgb = ks * 4 + grp;
    const float* xs = x + (size_t)(n0w + row16) * 512 + fgb * 8;
    float4 xv0 = ((const float4*)xs)[0];
    float4 xv1 = ((const float4*)xs)[1];
    u32 ax[4];
    ax[0] = (u32)f2h(xv0.x) | ((u32)f2h(xv0.y) << 16);
    ax[1] = (u32)f2h(xv0.z) | ((u32)f2h(xv0.w) << 16);
    ax[2] = (u32)f2h(xv1.x) | ((u32)f2h(xv1.y) << 16);
    ax[3] = (u32)f2h(xv1.z) | ((u32)f2h(xv1.w) << 16);
    half8 af = pk2h8(*(uint4*)ax);
    #pragma unroll
    for (int nt = 0; nt < 4; ++nt){
      half8 bf = *(const half8*)(wLDS + ((size_t)fgb * 64 + nt * 16 + row16) * 8);
      acc[nt] = __builtin_amdgcn_mfma_f32_16x16x32_f16(af, bf, acc[nt], 0, 0, 0);
    }
  }
  // ---- scale-free score tables ----
  float a1v[4], a2v[4];
  #pragma unroll
  for (int nt = 0; nt < 4; ++nt){
    a1v[nt] = av[h * 128 + nt * 16 + row16];
    a2v[nt] = av[h * 128 + 64 + nt * 16 + row16];
  }
  #pragma unroll
  for (int r = 0; r < 4; ++r){
    float p1 = acc[0][r]*a1v[0] + acc[1][r]*a1v[1] + acc[2][r]*a1v[2] + acc[3][r]*a1v[3];
    float p2 = acc[0][r]*a2v[0] + acc[1][r]*a2v[1] + acc[2][r]*a2v[2] + acc[3][r]*a2v[3];
    #pragma unroll
    for (int d = 1; d < 16; d <<= 1){ p1 += __shfl_xor(p1, d, 64); p2 += __shfl_xor(p2, d, 64); }
    if (row16 == 0){
      int idx = h * 4096 + n0w + grp * 4 + r;
      r1[idx]    = __expf(-0.8f * p1);     // row scale e^{-0.8 s1}
      e21h[idx]  = f2h(__expf(p2));
      e202h[idx] = f2h(__expf(0.2f * p2));
    }
  }
  // ---- whB f16 pack via LDS transpose ----
  #pragma unroll
  for (int nt = 0; nt < 4; ++nt)
    #pragma unroll
    for (int r = 0; r < 4; ++r){
      int jl = wv * 16 + grp * 4 + r;
      int o  = nt * 16 + row16;
      tr[((jl >> 3) * 64 + o) * 8 + (jl & 7)] = f2h(acc[nt][r]);
    }
  __syncthreads();
  u16* dst = whB + (size_t)h * 262144 + (size_t)n0 * 64;
  #pragma unroll
  for (int q = 0; q < 2; ++q)
    *(uint4*)(dst + (tid * 2 + q) * 8) = *(const uint4*)(tr + (tid * 2 + q) * 8);

  // ---- adj-pack slice (transposed bitmask; no data dep on gemm) ----
  {
    int B = blockIdx.y * 64 + blockIdx.x;   // 0..511
    int uid0 = B * 512 + wv * 128;
    for (int k = 0; k < 128; k += 8){
      int v[8];
      #pragma unroll
      for (int q = 0; q < 8; ++q){
        int uid = uid0 + k + q;
        v[q] = adj[(size_t)(uid >> 6) * 4096 + ((uid & 63) << 6) + lane];
      }
      u64 m[8];
      #pragma unroll
      for (int q = 0; q < 8; ++q) m[q] = __ballot(v[q] != 0);
      if (lane == 0){
        #pragma unroll
        for (int q = 0; q < 8; ++q){
          int uid = uid0 + k + q;
          bits_t[(size_t)(uid & 63) * 4096 + (uid >> 6)] = m[q];
        }
      }
    }
  }
}

// ===== K2: layer-1 attention (R7 structure, f16 + packed w-gen) ============
__global__ __launch_bounds__(256) void k_att1(const u16* __restrict__ whB,
                                              const u64* __restrict__ bits_t,
                                              const float* __restrict__ r1,
                                              const u16* __restrict__ e21h, const u16* __restrict__ e202h,
                                              u16* __restrict__ pnum, float* __restrict__ pden){
  __shared__ u16  smB[2][4096];            // 64 j x 64 o f16, [j/8][o][j&7]
  __shared__ u32  smT[2][2][64];           // staged f16 tables
  __shared__ u32  smLut[4];
  int h     = blockIdx.y;
  int iblk  = blockIdx.x;
  int split = blockIdx.z;
  int lane = threadIdx.x & 63;
  int wv   = threadIdx.x >> 6;
  int row16 = lane & 15, grp = lane >> 4;
  if (threadIdx.x < 4)
    smLut[threadIdx.x] = ((threadIdx.x & 1) ? 0xFFFFu : 0u) | ((threadIdx.x & 2) ? 0xFFFF0000u : 0u);
  int i = iblk * 64 + wv * 16 + row16;
  int hoff = h * 4096;
  u32 rb = (u32)f2h(r1[hoff + i]); rb |= rb << 16;
  h2 rr = u2h2(rb);
  const u16* whBh = whB + (size_t)h * 262144;
  int jbeg = split * 1024;

  half8 bden;                              // ones-column B frag for den
  {
    u32 z[4] = {0,0,0,0};
    if (row16 == 0){ z[0]=0x3C003C00u; z[1]=0x3C003C00u; z[2]=0x3C003C00u; z[3]=0x3C003C00u; }
    bden = pk2h8(*(uint4*)z);
  }

  auto stage = [&](int bb, int j0){
    const char* g = (const char*)whBh + (size_t)j0 * 128 + wv * 2048 + lane * 16;
    char* l = (char*)(&smB[bb][0]) + wv * 2048;
    async16(l, g);
    async16(l + 1024, g + 1024);
    if (wv == 0)      async4(&smT[bb][0][0], (const char*)(e21h  + hoff + j0) + lane * 4);
    else if (wv == 1) async4(&smT[bb][1][0], (const char*)(e202h + hoff + j0) + lane * 4);
  };

  f32x4 acc[4] = {};
  f32x4 accden = {};
  stage(0, jbeg);
  for (int c = 0; c < 16; ++c){
    int bb = c & 1;
    u64 mrow = bits_t[(size_t)(split * 16 + c) * 4096 + i];   // coalesced
    __syncthreads();                       // buf bb staged; buf bb^1 free
    if (c < 15) stage(bb ^ 1, jbeg + (c + 1) * 64);
    #pragma unroll
    for (int ks = 0; ks < 2; ++ks){
      uint4 e1q = *(const uint4*)((const char*)&smT[bb][0][0] + ks * 64 + grp * 16);
      uint4 e2q = *(const uint4*)((const char*)&smT[bb][1][0] + ks * 64 + grp * 16);
      u32 es[4] = {e1q.x, e1q.y, e1q.z, e1q.w};
      u32 gs[4] = {e2q.x, e2q.y, e2q.z, e2q.w};
      const u16* bbase = &smB[bb][(ks * 4 + grp) * 512];
      half8 bf0 = *(const half8*)(bbase + (0 * 16 + row16) * 8);
      half8 bf1 = *(const half8*)(bbase + (1 * 16 + row16) * 8);
      half8 bf2 = *(const half8*)(bbase + (2 * 16 + row16) * 8);
      half8 bf3 = *(const half8*)(bbase + (3 * 16 + row16) * 8);
      u32 mb = ((u32)(mrow >> (ks * 32)) >> (grp * 8)) & 0xffu;
      u32 pk[4];
      #pragma unroll
      for (int t2i = 0; t2i < 4; ++t2i){
        h2 w = __builtin_elementwise_max(u2h2(es[t2i]), rr * u2h2(gs[t2i]));
        pk[t2i] = h22u(w) & smLut[(mb >> (2 * t2i)) & 3u];
      }
      half8 af = pk2h8(*(uint4*)pk);
      acc[0] = __builtin_amdgcn_mfma_f32_16x16x32_f16(af, bf0, acc[0], 0, 0, 0);
      acc[1] = __builtin_amdgcn_mfma_f32_16x16x32_f16(af, bf1, acc[1], 0, 0, 0);
      acc[2] = __builtin_amdgcn_mfma_f32_16x16x32_f16(af, bf2, acc[2], 0, 0, 0);
      acc[3] = __builtin_amdgcn_mfma_f32_16x16x32_f16(af, bf3, acc[3], 0, 0, 0);
      accden = __builtin_amdgcn_mfma_f32_16x16x32_f16(af, bden, accden, 0, 0, 0);
    }
  }

  #pragma unroll
  for (int r4 = 0; r4 < 4; ++r4){
    int n = iblk * 64 + wv * 16 + grp * 4 + r4;
    if (row16 == 0)
      pden[((size_t)split * 8 + h) * 4096 + n] = accden[r4];
    u16* dst = pnum + ((size_t)split * 4096 + n) * 512 + h * 64 + row16;
    #pragma unroll
    for (int nt = 0; nt < 4; ++nt)
      dst[nt * 16] = f2h(acc[nt][r4]);
  }
}

// ===== K3: combine + Who = h @ Wout + layer-2 tables =======================
__global__ __launch_bounds__(256) void k_gemm2(const u16* __restrict__ pnum,
                                               const float* __restrict__ pden,
                                               const float* __restrict__ Wout,
                                               const float* __restrict__ aout,
                                               u16* __restrict__ whoB,
                                               float* __restrict__ r1o,
                                               u16* __restrict__ e21oh, u16* __restrict__ e202oh){
  __shared__ float Wl[8192];                  // 512 x 16
  __shared__ float hrow[16 * 516];            // combined+elu rows, padded stride
  __shared__ float sden[128];                 // den[h][n]
  int n0 = blockIdx.x * 16;
  for (int t = threadIdx.x; t < 8192; t += 256) Wl[t] = Wout[t];
  if (threadIdx.x < 128){
    int hh = threadIdx.x >> 4, nn = threadIdx.x & 15;
    float d = 0.f;
    #pragma unroll
    for (int s = 0; s < 4; ++s) d += pden[((size_t)s * 8 + hh) * 4096 + n0 + nn];
    sden[threadIdx.x] = d;
  }
  __syncthreads();
  {
    int nn = threadIdx.x >> 4;
    int fc = threadIdx.x & 15;
    int f0 = fc * 32;
    int hh = fc >> 1;
    float dinv = 1.f / sden[hh * 16 + nn];
    float v[32];
    #pragma unroll
    for (int k = 0; k < 32; ++k) v[k] = 0.f;
    #pragma unroll
    for (int s = 0; s < 4; ++s){
      const u16* p = pnum + ((size_t)s * 4096 + n0 + nn) * 512 + f0;
      #pragma unroll
      for (int q = 0; q < 4; ++q){
        uint4 raw = *(const uint4*)(p + q * 8);
        u32 rw[4] = {raw.x, raw.y, raw.z, raw.w};
        #pragma unroll
        for (int d2 = 0; d2 < 4; ++d2){
          h2 dh = u2h2(rw[d2]);
          v[q * 8 + d2 * 2]     += (float)dh.x;
          v[q * 8 + d2 * 2 + 1] += (float)dh.y;
        }
      }
    }
    #pragma unroll
    for (int k = 0; k < 32; ++k){
      float val = v[k] * dinv;
      val = val > 0.f ? val : (__expf(val) - 1.f);
      hrow[nn * 516 + f0 + k] = val;
    }
  }
  __syncthreads();
  int c  = threadIdx.x & 15;
  int rl = threadIdx.x >> 4;
  int n = n0 + rl;
  const float4* hr = (const float4*)(hrow + rl * 516);
  float acc = 0.f;
  #pragma unroll 8
  for (int f4 = 0; f4 < 128; ++f4){
    float4 hv = hr[f4];
    int f = f4 * 4;
    acc += hv.x * Wl[f * 16 + c] + hv.y * Wl[(f + 1) * 16 + c]
         + hv.z * Wl[(f + 2) * 16 + c] + hv.w * Wl[(f + 3) * 16 + c];
  }
  whoB[((size_t)(n >> 3) * 16 + c) * 8 + (n & 7)] = f2h(acc);
  float p1 = acc * aout[c], p2 = acc * aout[16 + c];
  #pragma unroll
  for (int d = 1; d < 16; d <<= 1){ p1 += __shfl_xor(p1, d, 64); p2 += __shfl_xor(p2, d, 64); }
  if (c == 0){
    r1o[n]    = __expf(-0.8f * p1);
    e21oh[n]  = f2h(__expf(p2));
    e202oh[n] = f2h(__expf(0.2f * p2));
  }
}

// ===== K4: layer-2 attention (16-way split, f16, global-direct) ============
__global__ __launch_bounds__(256) void k_att2(const u16* __restrict__ whoB,
                                              const u64* __restrict__ bits_t,
                                              const float* __restrict__ r1o,
                                              const u16* __restrict__ e21oh, const u16* __restrict__ e202oh,
                                              float* __restrict__ pnum, float* __restrict__ pden){
  __shared__ u32 smLut[4];
  int iblk  = blockIdx.x;
  int split = blockIdx.y;                     // 0..15
  int lane = threadIdx.x & 63;
  int wv   = threadIdx.x >> 6;
  int row16 = lane & 15, grp = lane >> 4;
  if (threadIdx.x < 4)
    smLut[threadIdx.x] = ((threadIdx.x & 1) ? 0xFFFFu : 0u) | ((threadIdx.x & 2) ? 0xFFFF0000u : 0u);
  __syncthreads();
  int i = iblk * 64 + wv * 16 + row16;
  u32 rb = (u32)f2h(r1o[i]); rb |= rb << 16;
  h2 rr = u2h2(rb);
  int jbeg = split * 256;
  half8 bden;
  {
    u32 z[4] = {0,0,0,0};
    if (row16 == 0){ z[0]=0x3C003C00u; z[1]=0x3C003C00u; z[2]=0x3C003C00u; z[3]=0x3C003C00u; }
    bden = pk2h8(*(uint4*)z);
  }

  f32x4 acc = {};
  f32x4 accden = {};
  #pragma unroll
  for (int c = 0; c < 4; ++c){
    int j0 = jbeg + c * 64;
    u64 mrow = bits_t[(size_t)(split * 4 + c) * 4096 + i];   // coalesced
    #pragma unroll
    for (int ks = 0; ks < 2; ++ks){
      int sb = (j0 >> 3) + ks * 4 + grp;
      half8 bf = *(const half8*)(whoB + ((size_t)sb * 16 + row16) * 8);
      uint4 e1q = *(const uint4*)(e21oh  + j0 + ks * 32 + grp * 8);
      uint4 e2q = *(const uint4*)(e202oh + j0 + ks * 32 + grp * 8);
      u32 es[4] = {e1q.x, e1q.y, e1q.z, e1q.w};
      u32 gs[4] = {e2q.x, e2q.y, e2q.z, e2q.w};
      u32 mb = ((u32)(mrow >> (ks * 32)) >> (grp * 8)) & 0xffu;
      u32 pk[4];
      #pragma unroll
      for (int t2i = 0; t2i < 4; ++t2i){
        h2 w = __builtin_elementwise_max(u2h2(es[t2i]), rr * u2h2(gs[t2i]));
        pk[t2i] = h22u(w) & smLut[(mb >> (2 * t2i)) & 3u];
      }
      half8 af = pk2h8(*(uint4*)pk);
      acc    = __builtin_amdgcn_mfma_f32_16x16x32_f16(af, bf, acc, 0, 0, 0);
      accden = __builtin_amdgcn_mfma_f32_16x16x32_f16(af, bden, accden, 0, 0, 0);
    }
  }
  #pragma unroll
  for (int r4 = 0; r4 < 4; ++r4){
    int n = iblk * 64 + wv * 16 + grp * 4 + r4;
    if (row16 == 0)
      pden[(size_t)n * 16 + split] = accden[r4];
    pnum[((size_t)n * 16 + split) * 16 + row16] = acc[r4];
  }
}

// ===== K5: combine + elu + log_softmax =====================================
__global__ __launch_bounds__(256) void k_final(const float* __restrict__ pnum,
                                               const float* __restrict__ pden,
                                               float* __restrict__ out){
  int tid = blockIdx.x * 256 + threadIdx.x;   // 65536
  int c = tid & 15;
  int n = tid >> 4;
  float num = 0.f, den = 0.f;
  #pragma unroll
  for (int s = 0; s < 16; ++s){
    num += pnum[((size_t)n * 16 + s) * 16 + c];
    den += pden[(size_t)n * 16 + s];
  }
  float v = num / den;
  v = v > 0.f ? v : (__expf(v) - 1.f);
  float m = v;
  #pragma unroll
  for (int d = 1; d < 16; d <<= 1) m = fmaxf(m, __shfl_xor(m, d, 64));
  float es = __expf(v - m), ss = es;
  #pragma unroll
  for (int d = 1; d < 16; d <<= 1) ss += __shfl_xor(ss, d, 64);
  out[(size_t)n * 16 + c] = v - m - __logf(ss);
}

// ---------------------------------------------------------------------------
extern "C" void kernel_launch(void* const* d_in, const int* in_sizes, int n_in,
                              void* d_out, int out_size, void* d_ws, size_t ws_size,
                              hipStream_t stream){
  (void)in_sizes; (void)n_in; (void)out_size; (void)ws_size;
  const float* x    = (const float*)d_in[0];
  const int*   adj  = (const int*)d_in[1];
  const float* W    = (const float*)d_in[2];
  const float* av   = (const float*)d_in[3];
  const float* Wout = (const float*)d_in[4];
  const float* aout = (const float*)d_in[5];
  float* out = (float*)d_out;
  char* ws = (char*)d_ws;

  u64*  bits_t  = (u64*)(ws + 0x0000000);        // 2 MB [64][4096]
  u16*  whB     = (u16*)(ws + 0x0200000);        // 4 MB f16 [8][j/8][o][8]
  float* r1     = (float*)(ws + 0x0600000);      // 128 KB
  u16*  e21h    = (u16*)(ws + 0x0620000);        // 64 KB f16
  u16*  e202h   = (u16*)(ws + 0x0630000);        // 64 KB f16
  u16*  pnum1   = (u16*)(ws + 0x0680000);        // 16 MB f16 [4][4096][512]
  float* pden1  = (float*)(ws + 0x1680000);      // 512 KB [4][8][4096]
  u16*  whoB    = (u16*)(ws + 0x1700000);        // 128 KB f16
  float* r1o    = (float*)(ws + 0x1720000);      // 16 KB
  u16*  e21oh   = (u16*)(ws + 0x1724000);        // 8 KB f16
  u16*  e202oh  = (u16*)(ws + 0x1726000);        // 8 KB f16
  float* pnum2  = (float*)(ws + 0x1730000);      // 4 MB [4096][16][16]
  float* pden2  = (float*)(ws + 0x1B30000);      // 256 KB

  k_gemm1<<<dim3(64, 8), dim3(256), 0, stream>>>(x, W, av, adj, whB, bits_t, r1, e21h, e202h);
  k_att1<<<dim3(64, 8, 4), dim3(256), 0, stream>>>(whB, bits_t, r1, e21h, e202h, pnum1, pden1);
  k_gemm2<<<dim3(256), dim3(256), 0, stream>>>(pnum1, pden1, Wout, aout, whoB, r1o, e21oh, e202oh);
  k_att2<<<dim3(64, 16), dim3(256), 0, stream>>>(whoB, bits_t, r1o, e21oh, e202oh, pnum2, pden2);
  k_final<<<dim3(256), dim3(256), 0, stream>>>(pnum2, pden2, out);
}